// Round 7
// baseline (214.426 us; speedup 1.0000x reference)
//
#include <hip/hip_runtime.h>

#define N_   8192
#define FIN  256
#define FOUT 128
#define NW   (N_ / 32)   // bitmask words per row = 256

typedef _Float16 f16x8 __attribute__((ext_vector_type(8)));
typedef float    f32x4 __attribute__((ext_vector_type(4)));
typedef unsigned int uint;

// LDS-only barrier: orders LDS without draining vmcnt (global prefetches
// survive). All vmem here is thread-private, so no cross-thread vmem hazard.
#define LDS_BARRIER() asm volatile("s_waitcnt lgkmcnt(0)\n\ts_barrier" ::: "memory")

// ---------------- Kernel 0: pack adj (int32 0/1) -> bitmask ------------------
__global__ __launch_bounds__(256) void k_pack(
    const int* __restrict__ adj, uint* __restrict__ bm)
{
    const int wid = (blockIdx.x * 256 + threadIdx.x) >> 6;   // row 0..8191
    const int l   = threadIdx.x & 63;
    const int4* __restrict__ arow = (const int4*)(adj + (size_t)wid * N_);
    uint* __restrict__ brow = bm + (size_t)wid * NW;

    #pragma unroll 2
    for (int jb = 0; jb < 32; ++jb) {
        int4 av = arow[jb * 64 + l];
        uint nib = (uint)(av.x != 0) | ((uint)(av.y != 0) << 1)
                 | ((uint)(av.z != 0) << 2) | ((uint)(av.w != 0) << 3);
        uint v = nib | (__shfl_xor(nib, 1, 64) << 4);
        v = v | (__shfl_xor(v, 2, 64) << 8);
        v = v | (__shfl_xor(v, 4, 64) << 16);
        if ((l & 7) == 0)
            brow[jb * 8 + (l >> 3)] = v;
    }
}

// ---------------- Kernel 1: Wh = h @ W, s1 = Wh@a1, s2 = Wh@a2 ----------------
// s1/s2 pre-scaled by 1/ln2 for exp2 in k_attn.
__global__ __launch_bounds__(256) void k_wh(
    const float* __restrict__ h, const float* __restrict__ W,
    const float* __restrict__ a, float* __restrict__ Wh,
    float* __restrict__ s1, float* __restrict__ s2)
{
    __shared__ float hrow[2][FIN];
    __shared__ float rbuf[2][2][2];
    const int t   = threadIdx.x;
    const int rh  = t >> 7;
    const int c   = t & 127;
    const int row = (blockIdx.x << 1) + rh;

    hrow[rh][c]       = h[(size_t)row * FIN + c];
    hrow[rh][c + 128] = h[(size_t)row * FIN + c + 128];
    __syncthreads();

    float acc = 0.f;
    #pragma unroll 8
    for (int k = 0; k < FIN; ++k)
        acc = fmaf(hrow[rh][k], W[k * FOUT + c], acc);

    Wh[(size_t)row * FOUT + c] = acc;

    float p1 = acc * a[c];
    float p2 = acc * a[FOUT + c];
    #pragma unroll
    for (int off = 32; off; off >>= 1) {
        p1 += __shfl_down(p1, off, 64);
        p2 += __shfl_down(p2, off, 64);
    }
    if ((t & 63) == 0) { rbuf[rh][c >> 6][0] = p1; rbuf[rh][c >> 6][1] = p2; }
    __syncthreads();
    if (c == 0) {
        const float k2 = 1.44269504088896f;  // 1/ln2
        s1[row] = (rbuf[rh][0][0] + rbuf[rh][1][0]) * k2;
        s2[row] = (rbuf[rh][0][1] + rbuf[rh][1][1]) * k2;
    }
}

// ---------------- Kernel 2: transpose+convert Wh -> WhT fp16 [128][8192] ------
__global__ __launch_bounds__(256) void k_tr(
    const float* __restrict__ Wh, _Float16* __restrict__ WhT)
{
    __shared__ float tile[64][129];
    const int t = threadIdx.x;
    const int rbase = blockIdx.x * 64;

    #pragma unroll
    for (int q = 0; q < 8; ++q) {
        int i4 = q * 256 + t;
        int r  = i4 >> 5;
        int c4 = (i4 & 31) * 4;
        *(float4*)&tile[r][c4] = *(const float4*)&Wh[(size_t)(rbase + r) * FOUT + c4];
    }
    __syncthreads();

    const int c = t >> 1, half = t & 1;
    _Float16 buf[32];
    #pragma unroll
    for (int r = 0; r < 32; ++r) buf[r] = (_Float16)tile[32 * half + r][c];
    #pragma unroll
    for (int q = 0; q < 4; ++q)
        *(f16x8*)&WhT[(size_t)c * N_ + rbase + 32 * half + 8 * q] = *(f16x8*)&buf[8 * q];
}

// ---------------- Kernel 3: fused masked-softmax numerator (MFMA) -------------
// Grid: 2048 = 512 row-blocks (16 rows) x 4 j-splits (2048 j each).
// Block: 256 thr = 4 waves (small independent barrier group); wave w owns
// output cols [32w, 32w+32). Per 128-j tile: B-issue -> A-issue -> next-tile
// computeP (hides B latency) -> MFMA x8 -> lgkm-only barrier.
__global__ __launch_bounds__(256, 5) void k_attn(
    const uint* __restrict__ bm, const _Float16* __restrict__ WhT,
    const float* __restrict__ s1g, const float* __restrict__ s2g,
    float* __restrict__ num_g, float* __restrict__ den_g)
{
    __shared__ _Float16 pP[2][16][128];   // 8 KB, chunk-XOR swizzled
    __shared__ float s2s[2048];           // 8 KB

    const int t  = threadIdx.x;
    const int w  = t >> 6;                 // wave 0..3 = col-group
    const int l  = t & 63;

    const int rb    = blockIdx.x & 511;
    const int sp    = blockIdx.x >> 9;
    const int rbase = rb * 16;
    const int jbase = sp * 2048;

    // stage s2 slice (8 KB): 256 thr x 8 floats
    *(float4*)&s2s[t * 8]     = *(const float4*)&s2g[jbase + t * 8];
    *(float4*)&s2s[t * 8 + 4] = *(const float4*)&s2g[jbase + t * 8 + 4];

    // p-compute mapping: thread owns row r, 8 j's at j0 = 8g
    const int r  = t >> 4;                 // 0..15
    const int g  = t & 15;
    const int j0 = g << 3;
    const int shift = (g & 3) * 8;
    const float s1r = s1g[rbase + r];
    const uint* __restrict__ brow =
        bm + (size_t)(rbase + r) * NW + sp * 64 + (g >> 2);
    _Float16* const wp = &pP[0][0][0] + r * 128 + 8 * (g ^ (r & 7));  // buf0 write addr

    // MFMA operand addressing
    const int ln15 = l & 15, lq = l >> 4;
    const _Float16* __restrict__ bp =
        WhT + (size_t)(32 * w + ln15) * N_ + jbase + 8 * lq;   // ng=0 cols
    const _Float16* const ap = &pP[0][0][0] + ln15 * 128;      // buf0 A base

    f32x4 acc0 = {0.f, 0.f, 0.f, 0.f};    // cols 32w..32w+15
    f32x4 acc1 = {0.f, 0.f, 0.f, 0.f};    // cols 32w+16..32w+31
    float denp = 0.f;

    // phase-A: 8 attention weights -> fp16 into LDS buf (bufOff = 0 or 1024 f16s... 2048)
    auto computeP = [&](uint mv, int tile, int bufO) {
        const float bias = -5.77078016f;   // -4/ln2
        const uint byte = mv >> shift;
        const float* s2p = &s2s[tile * 128 + j0];
        float4 sA = *(const float4*)(s2p);
        float4 sB = *(const float4*)(s2p + 4);
        float m, e;
        f16x8 pv;
        m = s1r + sA.x; e = fmaxf(m, 0.2f * m); pv[0] = (_Float16)((byte & 1u)   ? __builtin_amdgcn_exp2f(e + bias) : 0.f);
        m = s1r + sA.y; e = fmaxf(m, 0.2f * m); pv[1] = (_Float16)((byte & 2u)   ? __builtin_amdgcn_exp2f(e + bias) : 0.f);
        m = s1r + sA.z; e = fmaxf(m, 0.2f * m); pv[2] = (_Float16)((byte & 4u)   ? __builtin_amdgcn_exp2f(e + bias) : 0.f);
        m = s1r + sA.w; e = fmaxf(m, 0.2f * m); pv[3] = (_Float16)((byte & 8u)   ? __builtin_amdgcn_exp2f(e + bias) : 0.f);
        m = s1r + sB.x; e = fmaxf(m, 0.2f * m); pv[4] = (_Float16)((byte & 16u)  ? __builtin_amdgcn_exp2f(e + bias) : 0.f);
        m = s1r + sB.y; e = fmaxf(m, 0.2f * m); pv[5] = (_Float16)((byte & 32u)  ? __builtin_amdgcn_exp2f(e + bias) : 0.f);
        m = s1r + sB.z; e = fmaxf(m, 0.2f * m); pv[6] = (_Float16)((byte & 64u)  ? __builtin_amdgcn_exp2f(e + bias) : 0.f);
        m = s1r + sB.w; e = fmaxf(m, 0.2f * m); pv[7] = (_Float16)((byte & 128u) ? __builtin_amdgcn_exp2f(e + bias) : 0.f);
        denp += (float)pv[0] + (float)pv[1] + (float)pv[2] + (float)pv[3]
              + (float)pv[4] + (float)pv[5] + (float)pv[6] + (float)pv[7];
        *(f16x8*)(wp + bufO) = pv;
    };

    // One tile step: mma tile (bufR) while computing P(tileN)->bufW.
    // B loads first, A ds_reads second, computeP VALU third, MFMAs last.
    auto tileStep = [&](int bufR, int jb, uint mvN, int tileN, int bufW) {
        const _Float16* bjb = bp + jb;
        f16x8 b00 = *(const f16x8*)(bjb);                 // ng0 kk0
        f16x8 b01 = *(const f16x8*)(bjb + 32);            // ng0 kk1
        f16x8 b02 = *(const f16x8*)(bjb + 64);
        f16x8 b03 = *(const f16x8*)(bjb + 96);
        f16x8 b10 = *(const f16x8*)(bjb + 16 * N_);       // ng1 kk0
        f16x8 b11 = *(const f16x8*)(bjb + 16 * N_ + 32);
        f16x8 b12 = *(const f16x8*)(bjb + 16 * N_ + 64);
        f16x8 b13 = *(const f16x8*)(bjb + 16 * N_ + 96);

        const _Float16* ab = ap + bufR * 2048;
        const int sw = (ln15 & 7);
        f16x8 a0 = *(const f16x8*)(ab + 8 * ((0 + lq) ^ sw));
        f16x8 a1 = *(const f16x8*)(ab + 8 * ((4 + lq) ^ sw));
        f16x8 a2 = *(const f16x8*)(ab + 8 * ((8 + lq) ^ sw));
        f16x8 a3 = *(const f16x8*)(ab + 8 * ((12 + lq) ^ sw));

        computeP(mvN, tileN, bufW * 2048);

        __builtin_amdgcn_s_setprio(1);
        acc0 = __builtin_amdgcn_mfma_f32_16x16x32_f16(a0, b00, acc0, 0, 0, 0);
        acc1 = __builtin_amdgcn_mfma_f32_16x16x32_f16(a0, b10, acc1, 0, 0, 0);
        acc0 = __builtin_amdgcn_mfma_f32_16x16x32_f16(a1, b01, acc0, 0, 0, 0);
        acc1 = __builtin_amdgcn_mfma_f32_16x16x32_f16(a1, b11, acc1, 0, 0, 0);
        acc0 = __builtin_amdgcn_mfma_f32_16x16x32_f16(a2, b02, acc0, 0, 0, 0);
        acc1 = __builtin_amdgcn_mfma_f32_16x16x32_f16(a2, b12, acc1, 0, 0, 0);
        acc0 = __builtin_amdgcn_mfma_f32_16x16x32_f16(a3, b03, acc0, 0, 0, 0);
        acc1 = __builtin_amdgcn_mfma_f32_16x16x32_f16(a3, b13, acc1, 0, 0, 0);
        __builtin_amdgcn_s_setprio(0);
    };

    // prologue: invariant into loop: buf0 = P(0), mv1 = mask(1)
    uint mv0 = brow[0];
    uint mv1 = brow[4];
    LDS_BARRIER();                   // s2s ready
    computeP(mv0, 0, 0);             // P(0) -> buf0
    LDS_BARRIER();

    // steady: pairs tt = 0..12; invariant at top: buf0=P(tt), mv1=mask(tt+1)
    for (int tt = 0; tt < 14; tt += 2) {
        mv0 = brow[(tt + 2) * 4];
        tileStep(0, tt * 128, mv1, tt + 1, 1);
        LDS_BARRIER();
        mv1 = brow[(tt + 3) * 4];
        tileStep(1, (tt + 1) * 128, mv0, tt + 2, 0);
        LDS_BARRIER();
    }
    // epilogue: buf0 = P(14), mv1 = mask(15)
    tileStep(0, 14 * 128, mv1, 15, 1);
    LDS_BARRIER();
    {   // tile 15 from buf1, no further P
        const _Float16* bjb = bp + 15 * 128;
        f16x8 b00 = *(const f16x8*)(bjb);
        f16x8 b01 = *(const f16x8*)(bjb + 32);
        f16x8 b02 = *(const f16x8*)(bjb + 64);
        f16x8 b03 = *(const f16x8*)(bjb + 96);
        f16x8 b10 = *(const f16x8*)(bjb + 16 * N_);
        f16x8 b11 = *(const f16x8*)(bjb + 16 * N_ + 32);
        f16x8 b12 = *(const f16x8*)(bjb + 16 * N_ + 64);
        f16x8 b13 = *(const f16x8*)(bjb + 16 * N_ + 96);
        const _Float16* ab = ap + 2048;
        const int sw = (ln15 & 7);
        f16x8 a0 = *(const f16x8*)(ab + 8 * ((0 + lq) ^ sw));
        f16x8 a1 = *(const f16x8*)(ab + 8 * ((4 + lq) ^ sw));
        f16x8 a2 = *(const f16x8*)(ab + 8 * ((8 + lq) ^ sw));
        f16x8 a3 = *(const f16x8*)(ab + 8 * ((12 + lq) ^ sw));
        acc0 = __builtin_amdgcn_mfma_f32_16x16x32_f16(a0, b00, acc0, 0, 0, 0);
        acc1 = __builtin_amdgcn_mfma_f32_16x16x32_f16(a0, b10, acc1, 0, 0, 0);
        acc0 = __builtin_amdgcn_mfma_f32_16x16x32_f16(a1, b01, acc0, 0, 0, 0);
        acc1 = __builtin_amdgcn_mfma_f32_16x16x32_f16(a1, b11, acc1, 0, 0, 0);
        acc0 = __builtin_amdgcn_mfma_f32_16x16x32_f16(a2, b02, acc0, 0, 0, 0);
        acc1 = __builtin_amdgcn_mfma_f32_16x16x32_f16(a2, b12, acc1, 0, 0, 0);
        acc0 = __builtin_amdgcn_mfma_f32_16x16x32_f16(a3, b03, acc0, 0, 0, 0);
        acc1 = __builtin_amdgcn_mfma_f32_16x16x32_f16(a3, b13, acc1, 0, 0, 0);
    }

    // ---- den: 16 threads per row are consecutive lanes ----
    denp += __shfl_xor(denp, 1, 64);
    denp += __shfl_xor(denp, 2, 64);
    denp += __shfl_xor(denp, 4, 64);
    denp += __shfl_xor(denp, 8, 64);
    if ((t & 15) == 0)
        den_g[(size_t)sp * N_ + rbase + r] = denp;

    // ---- num: unnormalized partial writes ----
    const int c0 = 32 * w + ln15;
    #pragma unroll
    for (int q = 0; q < 4; ++q) {
        num_g[((size_t)sp * N_ + rbase + 4 * lq + q) * FOUT + c0]      = acc0[q];
        num_g[((size_t)sp * N_ + rbase + 4 * lq + q) * FOUT + c0 + 16] = acc1[q];
    }
}

// ---------------- Kernel 4: combine j-splits and normalize --------------------
__global__ __launch_bounds__(256) void k_norm(
    const float* __restrict__ num_g, const float* __restrict__ den_g,
    float* __restrict__ out)
{
    const int idx4 = blockIdx.x * 256 + threadIdx.x;
    const int i  = idx4 >> 5;
    const int c4 = (idx4 & 31) * 4;

    float4 s = {0.f, 0.f, 0.f, 0.f};
    float  d = 0.f;
    #pragma unroll
    for (int sp = 0; sp < 4; ++sp) {
        float4 v = *(const float4*)(num_g + ((size_t)sp * N_ + i) * FOUT + c4);
        s.x += v.x; s.y += v.y; s.z += v.z; s.w += v.w;
        d += den_g[(size_t)sp * N_ + i];
    }
    const float inv = 1.f / d;
    float4 o = {s.x * inv, s.y * inv, s.z * inv, s.w * inv};
    *(float4*)&out[(size_t)i * FOUT + c4] = o;
}

extern "C" void kernel_launch(void* const* d_in, const int* in_sizes, int n_in,
                              void* d_out, int out_size, void* d_ws, size_t ws_size,
                              hipStream_t stream) {
    const float* h   = (const float*)d_in[0];
    const int*   adj = (const int*)d_in[1];
    const float* W   = (const float*)d_in[2];
    const float* a   = (const float*)d_in[3];
    float* out = (float*)d_out;

    char* ws = (char*)d_ws;
    float*    Wh  = (float*)ws;                           // 4 MB
    _Float16* WhT = (_Float16*)(ws + (4u << 20));         // 2 MB
    float*    s1  = (float*)(ws + (6u << 20));            // 32 KB
    float*    s2  = (float*)(ws + (6u << 20) + 32768);    // 32 KB
    float*    num = (float*)(ws + (7u << 20));            // 16 MB
    float*    den = (float*)(ws + (23u << 20));           // 128 KB
    uint*     bmk = (uint*)(ws + (24u << 20));            // 8 MB

    k_pack<<<2048,   256, 0, stream>>>(adj, bmk);
    k_wh  <<<N_ / 2, 256, 0, stream>>>(h, W, a, Wh, s1, s2);
    k_tr  <<<N_ / 64, 256, 0, stream>>>(Wh, WhT);
    k_attn<<<2048,  256, 0, stream>>>(bmk, WhT, s1, s2, num, den);
    k_norm<<<1024,  256, 0, stream>>>(num, den, out);
}

// Round 8
// 163.476 us; speedup vs baseline: 1.3117x; 1.3117x over previous
//
#include <hip/hip_runtime.h>

#define N_   8192
#define FIN  256
#define FOUT 128

typedef _Float16 f16x8 __attribute__((ext_vector_type(8)));
typedef float    f32x4 __attribute__((ext_vector_type(4)));
typedef unsigned int uint;

// ---------------- Kernel 1: Wh = h @ W, s1 = Wh@a1, s2 = Wh@a2 ----------------
// s1/s2 pre-scaled by 1/ln2 for exp2 in k_attn.
__global__ __launch_bounds__(256) void k_wh(
    const float* __restrict__ h, const float* __restrict__ W,
    const float* __restrict__ a, float* __restrict__ Wh,
    float* __restrict__ s1, float* __restrict__ s2)
{
    __shared__ float hrow[2][FIN];
    __shared__ float rbuf[2][2][2];
    const int t   = threadIdx.x;
    const int rh  = t >> 7;
    const int c   = t & 127;
    const int row = (blockIdx.x << 1) + rh;

    hrow[rh][c]       = h[(size_t)row * FIN + c];
    hrow[rh][c + 128] = h[(size_t)row * FIN + c + 128];
    __syncthreads();

    float acc = 0.f;
    #pragma unroll 8
    for (int k = 0; k < FIN; ++k)
        acc = fmaf(hrow[rh][k], W[k * FOUT + c], acc);

    Wh[(size_t)row * FOUT + c] = acc;

    float p1 = acc * a[c];
    float p2 = acc * a[FOUT + c];
    #pragma unroll
    for (int off = 32; off; off >>= 1) {
        p1 += __shfl_down(p1, off, 64);
        p2 += __shfl_down(p2, off, 64);
    }
    if ((t & 63) == 0) { rbuf[rh][c >> 6][0] = p1; rbuf[rh][c >> 6][1] = p2; }
    __syncthreads();
    if (c == 0) {
        const float k2 = 1.44269504088896f;  // 1/ln2
        s1[row] = (rbuf[rh][0][0] + rbuf[rh][1][0]) * k2;
        s2[row] = (rbuf[rh][0][1] + rbuf[rh][1][1]) * k2;
    }
}

// ------- Kernel 2: transpose+convert Wh -> j-tiled fp16 WhTt[j/32][128][32] ---
// B-fragment loads in k_attn then read 1 KB fully-contiguous per instruction.
__global__ __launch_bounds__(256) void k_tr(
    const float* __restrict__ Wh, _Float16* __restrict__ WhTt)
{
    __shared__ float tile[64][129];
    const int t = threadIdx.x;
    const int rbase = blockIdx.x * 64;      // j-range [rbase, rbase+64)

    #pragma unroll
    for (int q = 0; q < 8; ++q) {
        int i4 = q * 256 + t;
        int r  = i4 >> 5;
        int c4 = (i4 & 31) * 4;
        *(float4*)&tile[r][c4] = *(const float4*)&Wh[(size_t)(rbase + r) * FOUT + c4];
    }
    __syncthreads();

    const int c = t >> 1, half = t & 1;     // col 0..127, j-half 0..1
    _Float16 buf[32];
    #pragma unroll
    for (int r = 0; r < 32; ++r) buf[r] = (_Float16)tile[32 * half + r][c];
    // tile index = rbase/32 + half; layout [tile][col][j%32]
    _Float16* dst = WhTt + (size_t)(rbase / 32 + half) * 4096 + c * 32;
    #pragma unroll
    for (int q = 0; q < 4; ++q)
        *(f16x8*)(dst + 8 * q) = *(f16x8*)&buf[8 * q];
}

// ---------------- Kernel 3: barrier-free fused attention numerator -----------
// 512 blocks x 256 thr = 2048 waves; wave = 16 rows x 2048-j split. NO LDS, NO
// barriers: lane l computes P[row=l&15][j=8*(l>>4)+e] -> that IS the MFMA
// A-fragment. 8 MFMAs/tile against 8 B-frags (j-tiled WhTt, contiguous loads).
// adj streamed from HBM with 2-tile-deep register prefetch (per row+tile the
// 4 q-lanes' int4 pairs coalesce to one 128B line).
__global__ __launch_bounds__(256) void k_attn(
    const int* __restrict__ adj, const _Float16* __restrict__ WhTt,
    const float* __restrict__ s1g, const float* __restrict__ s2g,
    float* __restrict__ num_g, float* __restrict__ den_g)
{
    const int t  = threadIdx.x;
    const int w  = t >> 6;
    const int l  = t & 63;
    const int ln15 = l & 15, lq = l >> 4;

    const int sp    = blockIdx.x >> 7;              // j-split 0..3
    const int rg    = (blockIdx.x & 127) * 4 + w;   // row-group 0..511
    const int rbase = rg * 16;
    const int jbase = sp * 2048;

    const float s1r = s1g[rbase + ln15];
    const int* __restrict__ arow =
        adj + (size_t)(rbase + ln15) * N_ + jbase + 8 * lq;
    const float* __restrict__ s2p = s2g + jbase + 8 * lq;
    const _Float16* __restrict__ bp =
        WhTt + (size_t)(jbase >> 5) * 4096 + ln15 * 32 + 8 * lq;

    f32x4 acc[8];
    #pragma unroll
    for (int g = 0; g < 8; ++g) acc[g] = (f32x4){0.f, 0.f, 0.f, 0.f};
    float denp = 0.f;

    auto LA = [&](int tile, int h) { return *(const int4*)(arow + tile * 32 + 4 * h); };
    auto LS = [&](int tile, int h) { return *(const float4*)(s2p + tile * 32 + 4 * h); };

    auto loadB = [&](f16x8* Bd, int tile) {
        const _Float16* p = bp + (size_t)tile * 4096;
        #pragma unroll
        for (int g = 0; g < 8; ++g) Bd[g] = *(const f16x8*)(p + g * 512);
    };

    // computeP: 8 weights -> fp16x8 == MFMA A-fragment (in register)
    auto computeP = [&](const int4& a0, const int4& a1,
                        const float4& sA, const float4& sB) -> f16x8 {
        const float bias = -5.77078016f;   // -4/ln2
        float m, e;
        f16x8 pv;
        m = s1r + sA.x; e = fmaxf(m, 0.2f * m); pv[0] = (_Float16)(a0.x ? __builtin_amdgcn_exp2f(e + bias) : 0.f);
        m = s1r + sA.y; e = fmaxf(m, 0.2f * m); pv[1] = (_Float16)(a0.y ? __builtin_amdgcn_exp2f(e + bias) : 0.f);
        m = s1r + sA.z; e = fmaxf(m, 0.2f * m); pv[2] = (_Float16)(a0.z ? __builtin_amdgcn_exp2f(e + bias) : 0.f);
        m = s1r + sA.w; e = fmaxf(m, 0.2f * m); pv[3] = (_Float16)(a0.w ? __builtin_amdgcn_exp2f(e + bias) : 0.f);
        m = s1r + sB.x; e = fmaxf(m, 0.2f * m); pv[4] = (_Float16)(a1.x ? __builtin_amdgcn_exp2f(e + bias) : 0.f);
        m = s1r + sB.y; e = fmaxf(m, 0.2f * m); pv[5] = (_Float16)(a1.y ? __builtin_amdgcn_exp2f(e + bias) : 0.f);
        m = s1r + sB.z; e = fmaxf(m, 0.2f * m); pv[6] = (_Float16)(a1.z ? __builtin_amdgcn_exp2f(e + bias) : 0.f);
        m = s1r + sB.w; e = fmaxf(m, 0.2f * m); pv[7] = (_Float16)(a1.w ? __builtin_amdgcn_exp2f(e + bias) : 0.f);
        denp += (float)pv[0] + (float)pv[1] + (float)pv[2] + (float)pv[3]
              + (float)pv[4] + (float)pv[5] + (float)pv[6] + (float)pv[7];
        return pv;
    };

    auto mmaAll = [&](const f16x8& af, const f16x8* B) {
        __builtin_amdgcn_s_setprio(1);
        #pragma unroll
        for (int g = 0; g < 8; ++g)
            acc[g] = __builtin_amdgcn_mfma_f32_16x16x32_f16(af, B[g], acc[g], 0, 0, 0);
        __builtin_amdgcn_s_setprio(0);
    };

    // pipeline state: aA=adj(t), aB=adj(t+1), sA=s2(t), Bc=B(t)
    int4   aA0 = LA(0, 0), aA1 = LA(0, 1);
    int4   aB0 = LA(1, 0), aB1 = LA(1, 1);
    float4 sA0 = LS(0, 0), sA1 = LS(0, 1);
    float4 sB0, sB1;
    f16x8  Bc[8], Bn[8];
    loadB(Bc, 0);

    for (int tt = 0; tt < 64; tt += 2) {
        {   // tile tt
            const int tn = (tt + 1 < 64) ? tt + 1 : 63;
            sB0 = LS(tn, 0); sB1 = LS(tn, 1);
            loadB(Bn, tn);
            f16x8 af = computeP(aA0, aA1, sA0, sA1);
            const int ta = (tt + 2 < 64) ? tt + 2 : 63;
            aA0 = LA(ta, 0); aA1 = LA(ta, 1);
            mmaAll(af, Bc);
        }
        {   // tile tt+1
            const int tn = (tt + 2 < 64) ? tt + 2 : 63;
            sA0 = LS(tn, 0); sA1 = LS(tn, 1);
            loadB(Bc, tn);
            f16x8 af = computeP(aB0, aB1, sB0, sB1);
            const int ta = (tt + 3 < 64) ? tt + 3 : 63;
            aB0 = LA(ta, 0); aB1 = LA(ta, 1);
            mmaAll(af, Bn);
        }
    }

    // den: combine the 4 q-lanes of each row
    denp += __shfl_xor(denp, 16, 64);
    denp += __shfl_xor(denp, 32, 64);
    if (l < 16)
        den_g[(size_t)sp * N_ + rbase + ln15] = denp;

    // num partials: C layout row = 4*lq+e, col = 16*g+ln15
    #pragma unroll
    for (int g = 0; g < 8; ++g) {
        #pragma unroll
        for (int e = 0; e < 4; ++e)
            num_g[((size_t)sp * N_ + rbase + 4 * lq + e) * FOUT + 16 * g + ln15] = acc[g][e];
    }
}

// ---------------- Kernel 4: combine j-splits and normalize --------------------
__global__ __launch_bounds__(256) void k_norm(
    const float* __restrict__ num_g, const float* __restrict__ den_g,
    float* __restrict__ out)
{
    const int idx4 = blockIdx.x * 256 + threadIdx.x;
    const int i  = idx4 >> 5;
    const int c4 = (idx4 & 31) * 4;

    float4 s = {0.f, 0.f, 0.f, 0.f};
    float  d = 0.f;
    #pragma unroll
    for (int sp = 0; sp < 4; ++sp) {
        float4 v = *(const float4*)(num_g + ((size_t)sp * N_ + i) * FOUT + c4);
        s.x += v.x; s.y += v.y; s.z += v.z; s.w += v.w;
        d += den_g[(size_t)sp * N_ + i];
    }
    const float inv = 1.f / d;
    float4 o = {s.x * inv, s.y * inv, s.z * inv, s.w * inv};
    *(float4*)&out[(size_t)i * FOUT + c4] = o;
}

extern "C" void kernel_launch(void* const* d_in, const int* in_sizes, int n_in,
                              void* d_out, int out_size, void* d_ws, size_t ws_size,
                              hipStream_t stream) {
    const float* h   = (const float*)d_in[0];
    const int*   adj = (const int*)d_in[1];
    const float* W   = (const float*)d_in[2];
    const float* a   = (const float*)d_in[3];
    float* out = (float*)d_out;

    char* ws = (char*)d_ws;
    float*    Wh   = (float*)ws;                           // 4 MB
    _Float16* WhTt = (_Float16*)(ws + (4u << 20));         // 2 MB
    float*    s1   = (float*)(ws + (6u << 20));            // 32 KB
    float*    s2   = (float*)(ws + (6u << 20) + 32768);    // 32 KB
    float*    num  = (float*)(ws + (7u << 20));            // 16 MB
    float*    den  = (float*)(ws + (23u << 20));           // 128 KB

    k_wh  <<<N_ / 2, 256, 0, stream>>>(h, W, a, Wh, s1, s2);
    k_tr  <<<N_ / 64, 256, 0, stream>>>(Wh, WhTt);
    k_attn<<<512,   256, 0, stream>>>(adj, WhTt, s1, s2, num, den);
    k_norm<<<1024,  256, 0, stream>>>(num, den, out);
}